// Round 3
// baseline (511.517 us; speedup 1.0000x reference)
//
#include <hip/hip_runtime.h>
#include <math.h>

// x fp32 [B=8, C=64, S=32*128*128=524288]
// norm over C, avg+max over S, relu, sigmoid(out^2) -> [B,C]
#define NC   64
#define NS   524288
#define NB   8
#define BPB  256               // blocks per batch
#define CHUNK 8                // chunks per block
#define P    256               // positions per chunk (64 lanes x float4)

// Register-resident + 2-deep ping-pong prefetch:
//  - wave w owns channels {4i+w}, lane k owns positions 4k..4k+3
//  - chunk c+1's 16 float4 loads are issued BEFORE chunk c's nsq consume
//  - raw s_barrier + lgkmcnt(0) only: prefetch loads stay in flight across
//    the barrier (no vmcnt(0) drain). Parity-double-buffered nsq exchange
//    keeps one-barrier-per-chunk race-free.
__global__ __launch_bounds__(256, 2)
void ca_partial(const float* __restrict__ x, float* __restrict__ ws) {
    __shared__ float nsq_s[2][4][P];

    const int b   = blockIdx.y;
    const int blk = blockIdx.x;
    const int t   = threadIdx.x;
    const int w   = t >> 6;     // wave id 0..3
    const int k   = t & 63;     // lane

    float run_sum[16], run_max[16];
    #pragma unroll
    for (int i = 0; i < 16; ++i) { run_sum[i] = 0.0f; run_max[i] = -INFINITY; }

    const float* xb = x + (size_t)b * NC * NS + (size_t)w * NS + 4 * k;

    float4 va[16], vb[16];

    // prologue: load chunk 0
    {
        const float* pb = xb + (size_t)(blk * CHUNK) * P;
        #pragma unroll
        for (int i = 0; i < 16; ++i)
            va[i] = *reinterpret_cast<const float4*>(pb + (size_t)(4 * i) * NS);
    }

    #pragma unroll
    for (int ch = 0; ch < CHUNK; ++ch) {
        float4* v = (ch & 1) ? vb : va;   // ch is a literal (full unroll) -> static
        float4* u = (ch & 1) ? va : vb;

        // ---- issue next chunk's loads first (stay in flight across barrier) ----
        if (ch + 1 < CHUNK) {
            const float* pb = xb + (size_t)((blk * CHUNK + ch + 1) * P);
            #pragma unroll
            for (int i = 0; i < 16; ++i)
                u[i] = *reinterpret_cast<const float4*>(pb + (size_t)(4 * i) * NS);
        }

        // ---- per-position norm^2 from current chunk ----
        float nx = 0.f, ny = 0.f, nz = 0.f, nw = 0.f;
        #pragma unroll
        for (int i = 0; i < 16; ++i) {
            nx = fmaf(v[i].x, v[i].x, nx);
            ny = fmaf(v[i].y, v[i].y, ny);
            nz = fmaf(v[i].z, v[i].z, nz);
            nw = fmaf(v[i].w, v[i].w, nw);
        }

        // ---- cross-wave nsq exchange (raw barrier, no vmcnt drain) ----
        const int par = ch & 1;
        *reinterpret_cast<float4*>(&nsq_s[par][w][4 * k]) = make_float4(nx, ny, nz, nw);
        asm volatile("s_waitcnt lgkmcnt(0)" ::: "memory");
        __builtin_amdgcn_s_barrier();
        asm volatile("" ::: "memory");

        const float4 q0 = *reinterpret_cast<const float4*>(&nsq_s[par][0][4 * k]);
        const float4 q1 = *reinterpret_cast<const float4*>(&nsq_s[par][1][4 * k]);
        const float4 q2 = *reinterpret_cast<const float4*>(&nsq_s[par][2][4 * k]);
        const float4 q3 = *reinterpret_cast<const float4*>(&nsq_s[par][3][4 * k]);
        const float rx = 1.0f / fmaxf(sqrtf(q0.x + q1.x + q2.x + q3.x), 1e-12f);
        const float ry = 1.0f / fmaxf(sqrtf(q0.y + q1.y + q2.y + q3.y), 1e-12f);
        const float rz = 1.0f / fmaxf(sqrtf(q0.z + q1.z + q2.z + q3.z), 1e-12f);
        const float rw = 1.0f / fmaxf(sqrtf(q0.w + q1.w + q2.w + q3.w), 1e-12f);

        // ---- normalize held registers, accumulate per-channel sum/max ----
        #pragma unroll
        for (int i = 0; i < 16; ++i) {
            run_sum[i] = fmaf(v[i].x, rx, run_sum[i]);
            run_sum[i] = fmaf(v[i].y, ry, run_sum[i]);
            run_sum[i] = fmaf(v[i].z, rz, run_sum[i]);
            run_sum[i] = fmaf(v[i].w, rw, run_sum[i]);
            const float m0 = fmaxf(v[i].x * rx, v[i].y * ry);
            const float m1 = fmaxf(v[i].z * rz, v[i].w * rw);
            run_max[i] = fmaxf(run_max[i], fmaxf(m0, m1));
        }
    }

    // ---- one-time wave butterfly reduce, lane 0 writes partials ----
    float* wp = ws + (size_t)(b * BPB + blk) * (2 * NC);
    #pragma unroll
    for (int i = 0; i < 16; ++i) {
        float s = run_sum[i];
        float m = run_max[i];
        #pragma unroll
        for (int d = 32; d > 0; d >>= 1) {
            s += __shfl_xor(s, d, 64);
            m = fmaxf(m, __shfl_xor(m, d, 64));
        }
        if (k == 0) {
            wp[4 * i + w]      = s;   // channel c = 4i+w
            wp[NC + 4 * i + w] = m;
        }
    }
}

// Reduce BPB partials per (b,c), apply relu + sigmoid(out^2).
__global__ __launch_bounds__(1024)
void ca_final(const float* __restrict__ ws, float* __restrict__ out) {
    __shared__ float fs[16][NC];
    __shared__ float fm[16][NC];

    const int b = blockIdx.x;
    const int t = threadIdx.x;
    const int c = t & 63;
    const int q = t >> 6;      // 0..15

    float s = 0.0f, m = -INFINITY;
    for (int blk = q; blk < BPB; blk += 16) {
        const float* w = ws + (size_t)(b * BPB + blk) * (2 * NC);
        s += w[c];
        m = fmaxf(m, w[NC + c]);
    }
    fs[q][c] = s;
    fm[q][c] = m;
    __syncthreads();

    if (t < NC) {
        float ts = 0.0f, tm = -INFINITY;
        #pragma unroll
        for (int q2 = 0; q2 < 16; ++q2) {
            ts += fs[q2][t];
            tm = fmaxf(tm, fm[q2][t]);
        }
        float avg = ts * (1.0f / (float)NS);
        float o   = fmaxf(avg + tm, 0.0f);
        float att = 1.0f / (1.0f + expf(-o * o));
        out[b * NC + t] = att;
    }
}

extern "C" void kernel_launch(void* const* d_in, const int* in_sizes, int n_in,
                              void* d_out, int out_size, void* d_ws, size_t ws_size,
                              hipStream_t stream) {
    const float* x = (const float*)d_in[0];
    float* ws  = (float*)d_ws;
    float* out = (float*)d_out;

    dim3 grid1(BPB, NB);
    ca_partial<<<grid1, 256, 0, stream>>>(x, ws);
    ca_final<<<NB, 1024, 0, stream>>>(ws, out);
}